// Round 1
// baseline (700.709 us; speedup 1.0000x reference)
//
#include <hip/hip_runtime.h>

typedef unsigned short ushort_t;
typedef __bf16 bf16_t;
typedef __attribute__((ext_vector_type(8))) __bf16 bf16x8;
typedef __attribute__((ext_vector_type(4))) float floatx4;

#define TOKS 100352   // 32*56*56

// ---------- helpers ----------
__device__ __forceinline__ ushort_t f2bf(float f) {
    union { float f; unsigned u; } a; a.f = f;
    unsigned r = a.u + 0x7fffu + ((a.u >> 16) & 1u);   // RNE
    return (ushort_t)(r >> 16);
}

__device__ __forceinline__ void async16(const void* g, void* l) {
    __builtin_amdgcn_global_load_lds(
        (const __attribute__((address_space(1))) unsigned int*)g,
        (__attribute__((address_space(3))) unsigned int*)l,
        16, 0, 0);
}

// window-layout token -> original token (shift +3 both axes). Bijection; used
// for both the LN1 gather and the proj-epilogue scatter.
__device__ __forceinline__ int win_to_orig(int t) {
    int b = t / 3136, rr = t - b * 3136;
    int w_ = rr / 49, pos = rr - w_ * 49;
    int wi = w_ >> 3, wj = w_ & 7;
    int ti = pos / 7, tj = pos - ti * 7;
    int h = wi * 7 + ti + 3; if (h >= 56) h -= 56;
    int w = wj * 7 + tj + 3; if (w >= 56) w -= 56;
    return b * 3136 + h * 56 + w;
}

// ---------- weight convert + fused rel-pos bias table ----------
__global__ void convert_kernel(const float* __restrict__ qkv_w, const float* __restrict__ proj_w,
                               const float* __restrict__ fc1_w, const float* __restrict__ fc2_w,
                               const float* __restrict__ rpb, const int* __restrict__ rel_idx,
                               ushort_t* __restrict__ wq, ushort_t* __restrict__ wp,
                               ushort_t* __restrict__ w1, ushort_t* __restrict__ w2,
                               float* __restrict__ bias_h) {
    int i = blockIdx.x * 256 + threadIdx.x;        // grid covers 262144
    if (i < 196608) wq[i] = f2bf(qkv_w[i]);
    if (i < 65536)  wp[i] = f2bf(proj_w[i]);
    if (i < 262144) { w1[i] = f2bf(fc1_w[i]); w2[i] = f2bf(fc2_w[i]); }
    if (i < 19208)  {                               // 8 heads * 2401
        int h = i / 2401, ij = i - h * 2401;
        bias_h[i] = rpb[rel_idx[ij] * 8 + h];
    }
}

// ---------- LayerNorm (one wave per token, float4 loads) ----------
// GATHER=1: out row t (window layout) gathers from shifted original token (LN1)
// GATHER=0: identity (LN2)
template <int GATHER>
__global__ __launch_bounds__(256) void ln_kernel(const float* __restrict__ xin,
                                                 const float* __restrict__ gw,
                                                 const float* __restrict__ gb,
                                                 ushort_t* __restrict__ outb) {
    const int wid = threadIdx.x >> 6, lane = threadIdx.x & 63;
    const int t_out = blockIdx.x * 4 + wid;
    const int t_in = GATHER ? win_to_orig(t_out) : t_out;
    const float4* src = (const float4*)(xin + (long)t_in * 256);
    float4 v = src[lane];
    float s  = v.x + v.y + v.z + v.w;
    float s2 = v.x*v.x + v.y*v.y + v.z*v.z + v.w*v.w;
    #pragma unroll
    for (int d = 32; d >= 1; d >>= 1) { s += __shfl_xor(s, d, 64); s2 += __shfl_xor(s2, d, 64); }
    float mu  = s * 0.00390625f;
    float var = s2 * 0.00390625f - mu * mu;
    float ry  = rsqrtf(var + 1e-5f);
    float4 w4 = ((const float4*)gw)[lane], b4 = ((const float4*)gb)[lane];
    unsigned long long p =
          (unsigned long long)f2bf((v.x - mu) * ry * w4.x + b4.x)
        | ((unsigned long long)f2bf((v.y - mu) * ry * w4.y + b4.y) << 16)
        | ((unsigned long long)f2bf((v.z - mu) * ry * w4.z + b4.z) << 32)
        | ((unsigned long long)f2bf((v.w - mu) * ry * w4.w + b4.w) << 48);
    ((unsigned long long*)(outb + (long)t_out * 256))[lane] = p;
}

// ---------- 128x128 MFMA GEMM (m97 structure) ----------
// A: [M][KD] bf16 row-major.  Bw: [N][KD] bf16 row-major (i.e. B^T, K-contiguous).
// MODE 0: out bf16 = acc + bias                       (QKV)
// MODE 1: out fp32 scatter win->orig, + bias + x_res  (proj + residual -> d_out)
// MODE 2: out bf16 = gelu(acc + bias)                 (fc1)
// MODE 3: out fp32 += acc + bias                      (fc2 += into d_out)
template <int MODE, int N_LD, int KD>
__global__ __launch_bounds__(256, 2) void gemm_kernel(const ushort_t* __restrict__ A,
                                                      const ushort_t* __restrict__ Bw,
                                                      const float* __restrict__ bias,
                                                      void* __restrict__ outp,
                                                      const float* __restrict__ x_res) {
    __shared__ __align__(16) ushort_t As[128 * 32];
    __shared__ __align__(16) ushort_t Bs[128 * 32];
    const int tid = threadIdx.x;
    const int lane = tid & 63;
    const int wid = tid >> 6;
    const int wm = wid & 1, wn = wid >> 1;
    const int l15 = lane & 15, quad = lane >> 4;
    const long tileM = (long)blockIdx.y * 128;
    const long tileN = (long)blockIdx.x * 128;

    floatx4 acc[4][4];
    #pragma unroll
    for (int i = 0; i < 4; i++)
        #pragma unroll
        for (int j = 0; j < 4; j++) acc[i][j] = {0.f, 0.f, 0.f, 0.f};

    // staging map: byte o in [0,4096): row o/64, 16B chunk (o%64); chunk2 rows +64
    const int o1 = tid * 16;
    const int r1 = o1 >> 6, c1 = (o1 & 63) >> 1;
    const ushort_t* Ar1 = A + (tileM + r1) * KD + c1;
    const ushort_t* Ar2 = A + (tileM + r1 + 64) * KD + c1;
    const ushort_t* Br1 = Bw + (tileN + r1) * KD + c1;
    const ushort_t* Br2 = Bw + (tileN + r1 + 64) * KD + c1;
    ushort_t* Ad1 = &As[o1 >> 1];
    ushort_t* Ad2 = &As[(o1 >> 1) + 2048];
    ushort_t* Bd1 = &Bs[o1 >> 1];
    ushort_t* Bd2 = &Bs[(o1 >> 1) + 2048];

    for (int k0 = 0; k0 < KD; k0 += 32) {
        async16(Ar1 + k0, Ad1);
        async16(Ar2 + k0, Ad2);
        async16(Br1 + k0, Bd1);
        async16(Br2 + k0, Bd2);
        __syncthreads();                  // compiler emits vmcnt(0) drain here
        bf16x8 af[4], bfr[4];
        #pragma unroll
        for (int mi = 0; mi < 4; mi++)
            af[mi] = *(const bf16x8*)&As[(wm * 64 + mi * 16 + l15) * 32 + quad * 8];
        #pragma unroll
        for (int nj = 0; nj < 4; nj++)
            bfr[nj] = *(const bf16x8*)&Bs[(wn * 64 + nj * 16 + l15) * 32 + quad * 8];
        #pragma unroll
        for (int mi = 0; mi < 4; mi++)
            #pragma unroll
            for (int nj = 0; nj < 4; nj++)
                acc[mi][nj] = __builtin_amdgcn_mfma_f32_16x16x32_bf16(af[mi], bfr[nj], acc[mi][nj], 0, 0, 0);
        __syncthreads();
    }

    #pragma unroll
    for (int mi = 0; mi < 4; mi++)
      #pragma unroll
      for (int nj = 0; nj < 4; nj++)
        #pragma unroll
        for (int r = 0; r < 4; r++) {
            long row = tileM + wm * 64 + mi * 16 + quad * 4 + r;
            long col = tileN + wn * 64 + nj * 16 + l15;
            float v = acc[mi][nj][r] + bias[col];
            if (MODE == 0) {
                ((ushort_t*)outp)[row * N_LD + col] = f2bf(v);
            } else if (MODE == 1) {
                int t_in = win_to_orig((int)row);
                long idx = (long)t_in * 256 + col;
                ((float*)outp)[idx] = v + x_res[idx];
            } else if (MODE == 2) {
                float g = 0.5f * v * (1.f + erff(v * 0.70710678118654752f));
                ((ushort_t*)outp)[row * N_LD + col] = f2bf(g);
            } else {
                ((float*)outp)[row * N_LD + col] += v;
            }
        }
}

// ---------- attention: one wave per (window, head); 49 padded to 64 ----------
__global__ __launch_bounds__(256, 2) void attn_kernel(const ushort_t* __restrict__ qkv,
                                                      const float* __restrict__ bias_h,
                                                      const float* __restrict__ mask,
                                                      ushort_t* __restrict__ attnout) {
    __shared__ __align__(16) ushort_t lds[4 * 6912];   // per wave: P[64][72] + Vt[32][72]
    const int tid = threadIdx.x, lane = tid & 63, wid = tid >> 6;
    ushort_t* Pl = &lds[wid * 6912];
    ushort_t* Vt = Pl + 64 * 72;
    const int whid = blockIdx.x * 4 + wid;             // 16384 window-heads
    const int win = whid >> 3, head = whid & 7;
    const int wimg = win & 63;
    const int l15 = lane & 15, quad = lane >> 4;
    const long base = (long)win * 49 * 768;

    // Q (A-frag) and K (B-frag) straight from global: 16B per lane, layout-exact
    bf16x8 qf[4], kf[4];
    #pragma unroll
    for (int t4 = 0; t4 < 4; t4++) {
        int tok = t4 * 16 + l15; if (tok > 48) tok = 48;
        const ushort_t* p = qkv + base + (long)tok * 768 + head * 32 + quad * 8;
        qf[t4] = *(const bf16x8*)p;          // Q at col offset 0
        kf[t4] = *(const bf16x8*)(p + 256);  // K at col offset 256
    }

    floatx4 S[4][4];
    #pragma unroll
    for (int mi = 0; mi < 4; mi++)
        #pragma unroll
        for (int nj = 0; nj < 4; nj++) {
            floatx4 z = {0.f, 0.f, 0.f, 0.f};
            S[mi][nj] = __builtin_amdgcn_mfma_f32_16x16x32_bf16(qf[mi], kf[nj], z, 0, 0, 0);
        }

    // stage V^T into LDS (stride 72 pads the 16-way conflict away); zero pad j>=49
    {
        int j = lane;
        int jc = j < 49 ? j : 48;
        const uint4* vsrc = (const uint4*)(qkv + base + (long)jc * 768 + 512 + head * 32);
        uint4 vz; vz.x = vz.y = vz.z = vz.w = 0u;
        #pragma unroll
        for (int q4 = 0; q4 < 4; q4++) {
            uint4 vv = (j < 49) ? vsrc[q4] : vz;
            int db = q4 * 8;
            Vt[(db+0)*72 + j] = (ushort_t)vv.x;  Vt[(db+1)*72 + j] = (ushort_t)(vv.x >> 16);
            Vt[(db+2)*72 + j] = (ushort_t)vv.y;  Vt[(db+3)*72 + j] = (ushort_t)(vv.y >> 16);
            Vt[(db+4)*72 + j] = (ushort_t)vv.z;  Vt[(db+5)*72 + j] = (ushort_t)(vv.z >> 16);
            Vt[(db+6)*72 + j] = (ushort_t)vv.w;  Vt[(db+7)*72 + j] = (ushort_t)(vv.w >> 16);
        }
    }

    // scale + rel-pos bias + shift mask; pad with -1e30
    const float scale = 0.17677669529663687f;          // 32^-0.5
    const float* bh = bias_h + head * 2401;
    const float* mk = mask + wimg * 2401;
    #pragma unroll
    for (int mi = 0; mi < 4; mi++)
      #pragma unroll
      for (int nj = 0; nj < 4; nj++)
        #pragma unroll
        for (int r = 0; r < 4; r++) {
            int i = mi * 16 + quad * 4 + r;
            int j = nj * 16 + l15;
            float s = -1e30f;
            if (i < 49 && j < 49) {
                int ij = i * 49 + j;
                s = S[mi][nj][r] * scale + bh[ij] + mk[ij];
            }
            S[mi][nj][r] = s;
        }

    // row softmax: row i lives on the 16 lanes of one quad-group -> xor {1,2,4,8}
    #pragma unroll
    for (int mi = 0; mi < 4; mi++)
      #pragma unroll
      for (int r = 0; r < 4; r++) {
          float m = fmaxf(fmaxf(S[mi][0][r], S[mi][1][r]), fmaxf(S[mi][2][r], S[mi][3][r]));
          #pragma unroll
          for (int d = 1; d < 16; d <<= 1) m = fmaxf(m, __shfl_xor(m, d, 64));
          float e[4], sum = 0.f;
          #pragma unroll
          for (int nj = 0; nj < 4; nj++) { e[nj] = __expf(S[mi][nj][r] - m); sum += e[nj]; }
          #pragma unroll
          for (int d = 1; d < 16; d <<= 1) sum += __shfl_xor(sum, d, 64);
          float rinv = 1.f / sum;
          int i = mi * 16 + quad * 4 + r;
          #pragma unroll
          for (int nj = 0; nj < 4; nj++) Pl[i * 72 + (nj * 16 + l15)] = f2bf(e[nj] * rinv);
      }

    __syncthreads();   // order LDS writes (P, Vt) before fragment reads

    floatx4 O[4][2];
    #pragma unroll
    for (int mi = 0; mi < 4; mi++) { O[mi][0] = {0.f,0.f,0.f,0.f}; O[mi][1] = {0.f,0.f,0.f,0.f}; }
    #pragma unroll
    for (int kc = 0; kc < 2; kc++) {
        bf16x8 pf[4], vf[2];
        #pragma unroll
        for (int mi = 0; mi < 4; mi++)
            pf[mi] = *(const bf16x8*)&Pl[(mi * 16 + l15) * 72 + kc * 32 + quad * 8];
        #pragma unroll
        for (int n2 = 0; n2 < 2; n2++)
            vf[n2] = *(const bf16x8*)&Vt[(n2 * 16 + l15) * 72 + kc * 32 + quad * 8];
        #pragma unroll
        for (int mi = 0; mi < 4; mi++)
            #pragma unroll
            for (int n2 = 0; n2 < 2; n2++)
                O[mi][n2] = __builtin_amdgcn_mfma_f32_16x16x32_bf16(pf[mi], vf[n2], O[mi][n2], 0, 0, 0);
    }

    #pragma unroll
    for (int mi = 0; mi < 4; mi++)
      #pragma unroll
      for (int n2 = 0; n2 < 2; n2++)
        #pragma unroll
        for (int r = 0; r < 4; r++) {
            int i = mi * 16 + quad * 4 + r;
            if (i < 49) {
                long orow = ((long)win * 49 + i) * 256 + head * 32 + n2 * 16 + l15;
                attnout[orow] = f2bf(O[mi][n2][r]);
            }
        }
}

// ---------- launcher ----------
extern "C" void kernel_launch(void* const* d_in, const int* in_sizes, int n_in,
                              void* d_out, int out_size, void* d_ws, size_t ws_size,
                              hipStream_t stream) {
    const float* x      = (const float*)d_in[0];
    const float* n1w    = (const float*)d_in[1];
    const float* n1b    = (const float*)d_in[2];
    const float* qkv_w  = (const float*)d_in[3];
    const float* qkv_b  = (const float*)d_in[4];
    const float* rpb    = (const float*)d_in[5];
    const float* proj_w = (const float*)d_in[6];
    const float* proj_b = (const float*)d_in[7];
    const float* n2w    = (const float*)d_in[8];
    const float* n2b    = (const float*)d_in[9];
    const float* fc1_w  = (const float*)d_in[10];
    const float* fc1_b  = (const float*)d_in[11];
    const float* fc2_w  = (const float*)d_in[12];
    const float* fc2_b  = (const float*)d_in[13];
    const int*   rel_idx= (const int*)d_in[14];
    const float* amask  = (const float*)d_in[15];

    // ws layout (peak 207.3 MB):
    char* ws = (char*)d_ws;
    ushort_t* wq   = (ushort_t*)(ws + 0);          //  393,216 B  qkv_w bf16
    ushort_t* wp   = (ushort_t*)(ws + 393216);     //  131,072 B  proj_w bf16
    ushort_t* w1   = (ushort_t*)(ws + 524288);     //  524,288 B  fc1_w bf16
    ushort_t* w2   = (ushort_t*)(ws + 1048576);    //  524,288 B  fc2_w bf16
    float*    bh   = (float*)   (ws + 1572864);    //   76,832 B  bias_h[8][2401]
    ushort_t* hwin = (ushort_t*)(ws + 1703936);    // 51,380,224 B  LN1-out (reused: attn_out)
    ushort_t* qkvb = (ushort_t*)(ws + 53084160);   // 154,140,672 B qkv (reused: h2 + h3 chunk)
    ushort_t* h2   = qkvb;                         // 51,380,224 B (LN2 out, after qkv dead)
    ushort_t* h3   = (ushort_t*)(ws + 104464384);  // 102,760,448 B (fc1 out, per half)

    convert_kernel<<<1024, 256, 0, stream>>>(qkv_w, proj_w, fc1_w, fc2_w, rpb, rel_idx,
                                             wq, wp, w1, w2, bh);
    // LN1 fused with shift+window partition (gather): hwin[t] = LN(x)[map(t)]
    ln_kernel<1><<<TOKS / 4, 256, 0, stream>>>(x, n1w, n1b, hwin);
    // QKV: (100352 x 256) x (256 -> 768)
    gemm_kernel<0, 768, 256><<<dim3(6, 784), 256, 0, stream>>>(hwin, wq, qkv_b, qkvb, nullptr);
    // attention (writes attn_out into the hwin region)
    attn_kernel<<<4096, 256, 0, stream>>>(qkvb, bh, amask, hwin);
    // proj + window-reverse/unshift scatter + residual -> d_out holds x1 (fp32)
    gemm_kernel<1, 256, 256><<<dim3(2, 784), 256, 0, stream>>>(hwin, wp, proj_b, d_out, x);
    // LN2
    ln_kernel<0><<<TOKS / 4, 256, 0, stream>>>((const float*)d_out, n2w, n2b, h2);
    // MLP in two row-halves (50176 rows each) to fit ws
    for (int c = 0; c < 2; c++) {
        gemm_kernel<2, 1024, 256><<<dim3(8, 392), 256, 0, stream>>>(
            h2 + (long)c * 50176 * 256, w1, fc1_b, h3, nullptr);
        gemm_kernel<3, 256, 1024><<<dim3(2, 392), 256, 0, stream>>>(
            h3, w2, fc2_b, (float*)d_out + (long)c * 50176 * 256, nullptr);
    }
    (void)in_sizes; (void)n_in; (void)out_size; (void)ws_size;
}